// Round 4
// baseline (1023.525 us; speedup 1.0000x reference)
//
#include <hip/hip_runtime.h>

// DGP-RF embeddings, fused MFMA. Round 12: 32x32x16 MFMA, halved op counts.
// R9/R10/R11 post-mortem: occupancy pushes AND source-level pipelining all
// regressed. The pipes won't overlap; so REDUCE the ops instead.
// R8 accounting: LDS ~225us (136 ops/chunk-wave, biggest term), VALU ~190us,
// MFMA ~103us, serial sum = 518 ~= 529 measured.
// R12: both GEMMs use 32x32x16 (2x FLOP per fragment byte):
//  - GEMM1 swaps operands (A=W1 rf-rows, B=X pt-cols) so C reg-quads hold 4
//    CONSECUTIVE RFs -> moments T-writes become packed b64/b32 (48 scalar ->
//    12 vector writes). T layout [point][rf] serves GEMM2 A-frags directly.
//  - per chunk-wave: GEMM1 64->32 LDS reads / 64->32 MFMA; GEMM2 24->12
//    reads / 48->24 MFMA. Total LDS 136->56 ops.
// Cost: W1/W2 read 2x via L2 (~5GB, hidden). Residency unchanged (LDS-capped
// 2 blk/CU, ~1024 unified regs/wave available -> hoisting is safe, NO
// launch_bounds tightening).
// Predicted: Mfma ~28, VALU ~45, conflicts <=1.2e7, fused ~370-430us.

#define NPTS   131072
#define SGRP   16384
#define DIN    256
#define NRF    1024
#define DOUT   128
#define MT     64            // points per WG
#define NWG    (NPTS / MT)   // 2048

#define XLD    264   // bf16 X row stride (528B = 33*16: odd 16B mult -> spread banks)
#define XQLD   264   // fp8 x^2 row stride
#define TMLD   72    // bf16 m' row stride (144B = 9*16: odd 16B mult)
#define TVLD   72    // fp8 v'/m'^2 row stride

typedef unsigned short ushort_t;
typedef unsigned char  uchar_t;
typedef __attribute__((ext_vector_type(8))) short bf16x8;
typedef __attribute__((ext_vector_type(16))) float f32x16;
typedef __attribute__((ext_vector_type(4))) float f32x4v;

__device__ __forceinline__ unsigned short f2bf(float f) {
  unsigned u = __float_as_uint(f);
  u += 0x7fffu + ((u >> 16) & 1u);   // round-to-nearest-even
  return (unsigned short)(u >> 16);
}

// pack 2 floats -> 2 fp8 e4m3 bytes into (HI? bytes 2,3 : bytes 0,1) of old
template <bool HI>
__device__ __forceinline__ unsigned cvt2_fp8(float a, float b, unsigned old) {
#if __has_builtin(__builtin_amdgcn_cvt_pk_fp8_f32)
  return __builtin_amdgcn_cvt_pk_fp8_f32(a, b, old, HI);
#else
  auto enc = [](float x) -> unsigned {
    if (!(x > 0.00097656f)) return 0u;
    if (x >= 448.f) return 0x7Eu;
    union { float f; unsigned u; } v; v.f = x;
    int e = (int)(v.u >> 23) - 127;
    if (e < -6) { int n = (int)(x * 512.f + 0.5f); return (unsigned)n; }
    v.u += 0x0007FFFFu + ((v.u >> 20) & 1u);
    e = (int)(v.u >> 23) - 127;
    if (e > 8) return 0x7Eu;
    return (unsigned)(((e + 7) << 3) | ((v.u >> 20) & 7u));
  };
  unsigned p = (enc(a) | (enc(b) << 8));
  return HI ? ((old & 0x0000ffffu) | (p << 16)) : ((old & 0xffff0000u) | p);
#endif
}

__device__ __forceinline__ float fast_rcp(float x) {
#if __has_builtin(__builtin_amdgcn_rcpf)
  return __builtin_amdgcn_rcpf(x);
#else
  return 1.0f / x;
#endif
}
__device__ __forceinline__ float fast_rsq(float x) {
#if __has_builtin(__builtin_amdgcn_rsqf)
  return __builtin_amdgcn_rsqf(x);
#else
  return rsqrtf(x);
#endif
}
__device__ __forceinline__ float fast_exp2(float x) {
#if __has_builtin(__builtin_amdgcn_exp2f)
  return __builtin_amdgcn_exp2f(x);
#else
  return exp2f(x);
#endif
}

// Exact Gaussian-ReLU moments (A&S 7.1.26 erf, one shared exp2).
__device__ __forceinline__ void relu_moments(float mu, float v,
                                             float& mo, float& vo) {
  float vpe = v + 1e-8f;
  float rsq = fast_rsq(vpe);
  float s   = vpe * rsq;
  float z   = mu * rsq;
  float E   = fast_exp2(-0.7213475204444817f * z * z);  // exp(-z^2/2)
  float x   = 0.70710678118654752f * fabsf(z);
  float t   = fast_rcp(fmaf(0.3275911f, x, 1.0f));
  float poly = t * fmaf(t, fmaf(t, fmaf(t, fmaf(t, 1.061405429f, -1.453152027f),
                                        1.421413741f), -0.284496736f), 0.254829592f);
  float q   = 0.5f * poly * E;
  float Phi = (z >= 0.0f) ? (1.0f - q) : q;
  float phi = 0.3989422804014327f * E;
  float sphi = s * phi;
  mo = fmaf(mu, Phi, sphi);
  float ey2 = fmaf(fmaf(mu, mu, v), Phi, mu * sphi);
  vo = fmaxf(fmaf(-mo, mo, ey2), 1e-6f);
}

// ---------------- kernel 0: detect whether X_idx is int32 or int64 -------------
__global__ void detect_idx_kernel(const unsigned* __restrict__ raw,
                                  int* __restrict__ flag) {
  __shared__ int any_nz;
  if (threadIdx.x == 0) any_nz = 0;
  __syncthreads();
  if (raw[2 * threadIdx.x + 1] != 0u) atomicOr(&any_nz, 1);
  __syncthreads();
  if (threadIdx.x == 0) *flag = (any_nz == 0) ? 1 : 0;   // 1 => int64
}

// ---------------- kernel 1: convert weights (bf16 mean path, fp8 var path) ----
__global__ __launch_bounds__(256) void convert_kernel(
    const float* __restrict__ W1mu, const float* __restrict__ W1var,
    const float* __restrict__ W2mu, const float* __restrict__ W2var,
    ushort_t* __restrict__ w1mu_bf, uchar_t* __restrict__ w1var8,
    ushort_t* __restrict__ w2mu_bf, uchar_t* __restrict__ w2b8,
    uchar_t* __restrict__ w2var8) {
  int i4 = (blockIdx.x * 256 + threadIdx.x) * 4;   // grid covers 262144
  {
    f32x4v m = *(const f32x4v*)(W1mu + i4);
    ushort4 b; b.x = f2bf(m[0]); b.y = f2bf(m[1]); b.z = f2bf(m[2]); b.w = f2bf(m[3]);
    *(ushort4*)(w1mu_bf + i4) = b;
    f32x4v v = *(const f32x4v*)(W1var + i4);
    unsigned p = cvt2_fp8<false>(v[0] * 256.f, v[1] * 256.f, 0u);
    p = cvt2_fp8<true>(v[2] * 256.f, v[3] * 256.f, p);
    *(unsigned*)(w1var8 + i4) = p;
  }
  if (i4 < NRF * DOUT) {
    f32x4v m = *(const f32x4v*)(W2mu + i4);
    f32x4v v = *(const f32x4v*)(W2var + i4);
    ushort4 b; b.x = f2bf(m[0]); b.y = f2bf(m[1]); b.z = f2bf(m[2]); b.w = f2bf(m[3]);
    *(ushort4*)(w2mu_bf + i4) = b;
    unsigned pb = cvt2_fp8<false>(fmaf(m[0], m[0], v[0]) * 256.f,
                                  fmaf(m[1], m[1], v[1]) * 256.f, 0u);
    pb = cvt2_fp8<true>(fmaf(m[2], m[2], v[2]) * 256.f,
                        fmaf(m[3], m[3], v[3]) * 256.f, pb);
    *(unsigned*)(w2b8 + i4) = pb;
    unsigned pv = cvt2_fp8<false>(v[0] * 256.f, v[1] * 256.f, 0u);
    pv = cvt2_fp8<true>(v[2] * 256.f, v[3] * 256.f, pv);
    *(unsigned*)(w2var8 + i4) = pv;
  }
}

// ---------------- kernel 2: fused DGP-RF block --------------------------------
__global__ __launch_bounds__(256, 2) void fused_kernel(
    const float* __restrict__ X,
    const unsigned* __restrict__ Xidx_raw,
    const ushort_t* __restrict__ W1mu, const uchar_t* __restrict__ W1var8,
    const ushort_t* __restrict__ W2mu, const uchar_t* __restrict__ W2b8,
    const uchar_t* __restrict__ W2var8,
    const int* __restrict__ flag64,
    float* __restrict__ acc_means, float* __restrict__ acc_vars) {
  __shared__ ushort_t Xb[MT * XLD];    // 33.8 KB bf16 x
  __shared__ uchar_t  Xq8[MT * XQLD];  // 16.9 KB fp8 x^2
  __shared__ ushort_t Tm[MT * TMLD];   //  9.2 KB bf16 m'    [point][rf]
  __shared__ uchar_t  Tv8[MT * TVLD];  //  4.6 KB fp8 v'     [point][rf]
  __shared__ uchar_t  T38[MT * TVLD];  //  4.6 KB fp8 m'^2   [point][rf]
  __shared__ int sidx[MT];

  const int tid = threadIdx.x;
  const int p0  = blockIdx.x * MT;
  const int is64 = *flag64;

  if (tid < MT) {
    int p = p0 + tid;
    sidx[tid] = (int)(is64 ? Xidx_raw[2 * (size_t)p] : Xidx_raw[p]);
  }
  // stage X tile: bf16 x and fp8 x^2, converted once here
#pragma unroll
  for (int i = 0; i < 16; ++i) {
    int idx4 = i * 256 + tid;       // 0..4095 (64 rows x 64 float4)
    int row  = idx4 >> 6;
    int c4   = idx4 & 63;
    f32x4v xv = *(const f32x4v*)(X + (size_t)(p0 + row) * DIN + c4 * 4);
    ushort4 b;
    b.x = f2bf(xv[0]); b.y = f2bf(xv[1]); b.z = f2bf(xv[2]); b.w = f2bf(xv[3]);
    *(ushort4*)(Xb + row * XLD + c4 * 4) = b;
    unsigned q = cvt2_fp8<false>(xv[0] * xv[0], xv[1] * xv[1], 0u);
    q = cvt2_fp8<true>(xv[2] * xv[2], xv[3] * xv[3], q);
    *(unsigned*)(Xq8 + row * XQLD + c4 * 4) = q;
  }
  __syncthreads();

  const int lane  = tid & 63;
  const int wave  = tid >> 6;
  const int col32 = lane & 31;    // MFMA 32-col lane id
  const int khalf = lane >> 5;    // K-half selector (elems khalf*8..+7)

  // GEMM1 roles: wave = (ptblk<<1) | rfblk. GEMM2: same ptblk; dout pair d0.
  const int rfblk = wave & 1;
  const int ptblk = wave >> 1;
  const int d0    = (wave & 1) * 2;
  const int ptA   = ptblk * 32 + col32;      // point row used by ALL phases

  f32x16 acc_mo[2], acc_vo[2];
#pragma unroll
  for (int d = 0; d < 2; ++d)
#pragma unroll
    for (int i = 0; i < 16; ++i) { acc_mo[d][i] = 0.f; acc_vo[d][i] = 0.f; }

#pragma unroll 1
  for (int c = 0; c < 16; ++c) {   // 16 chunks x 64 RFs
    // ---- GEMM1: A = W1 (rf rows rfblk*32+col32), B = X (pt cols) ----
    const ushort_t* w1m = W1mu   + (size_t)(c * 64 + rfblk * 32 + col32) * DIN + khalf * 8;
    const uchar_t*  w1v = W1var8 + (size_t)(c * 64 + rfblk * 32 + col32) * DIN + khalf * 8;
    bf16x8 w1f[16]; long long w1q[16];
#pragma unroll
    for (int k = 0; k < 16; ++k) {
      w1f[k] = *(const bf16x8*)(w1m + k * 16);
      w1q[k] = *(const long long*)(w1v + k * 16);
    }
    f32x16 am, av;
#pragma unroll
    for (int i = 0; i < 16; ++i) { am[i] = 0.f; av[i] = 0.f; }
#pragma unroll
    for (int k = 0; k < 16; ++k) {
      bf16x8 bx = *(const bf16x8*)(Xb + ptA * XLD + k * 16 + khalf * 8);
      long long bq = *(const long long*)(Xq8 + ptA * XQLD + k * 16 + khalf * 8);
      am = __builtin_amdgcn_mfma_f32_32x32x16_bf16(w1f[k], bx, am, 0, 0, 0);
      av = __builtin_amdgcn_mfma_f32_32x32x16_fp8_fp8(w1q[k], bq, av, 0, 0, 0);
    }

    // ---- preload GEMM2 B (global; latency overlaps moments+barriers) ----
    bf16x8 b2m[4][2]; long long b2b[4][2], b2v[4][2];
#pragma unroll
    for (int d = 0; d < 2; ++d) {
      size_t wb = (size_t)((d0 + d) * 32 + col32) * NRF + c * 64 + khalf * 8;
#pragma unroll
      for (int ks = 0; ks < 4; ++ks) {
        b2m[ks][d] = *(const bf16x8*)(W2mu + wb + ks * 16);
        b2b[ks][d] = *(const long long*)(W2b8 + wb + ks * 16);
        b2v[ks][d] = *(const long long*)(W2var8 + wb + ks * 16);
      }
    }

    // Barrier A: prior chunk's GEMM2 T-reads complete before overwrite.
    __syncthreads();

    // ---- ReLU moments -> packed T-writes (reg-quad = 4 consecutive rfs) ----
    const int rfb = rfblk * 32 + 4 * khalf;   // chunk-local rf base
#pragma unroll
    for (int qi = 0; qi < 4; ++qi) {
      float mo0, vo0, mo1, vo1, mo2, vo2, mo3, vo3;
      relu_moments(am[4 * qi + 0], av[4 * qi + 0] * 0.00390625f, mo0, vo0);
      relu_moments(am[4 * qi + 1], av[4 * qi + 1] * 0.00390625f, mo1, vo1);
      relu_moments(am[4 * qi + 2], av[4 * qi + 2] * 0.00390625f, mo2, vo2);
      relu_moments(am[4 * qi + 3], av[4 * qi + 3] * 0.00390625f, mo3, vo3);
      unsigned lo = (unsigned)f2bf(mo0) | ((unsigned)f2bf(mo1) << 16);
      unsigned hi = (unsigned)f2bf(mo2) | ((unsigned)f2bf(mo3) << 16);
      unsigned long long tmq = (unsigned long long)lo | ((unsigned long long)hi << 32);
      *(unsigned long long*)(Tm + ptA * TMLD + rfb + 8 * qi) = tmq;
      unsigned tvq = cvt2_fp8<false>(vo0, vo1, 0u);
      tvq = cvt2_fp8<true>(vo2, vo3, tvq);
      *(unsigned*)(Tv8 + ptA * TVLD + rfb + 8 * qi) = tvq;
      unsigned t3q = cvt2_fp8<false>(mo0 * mo0, mo1 * mo1, 0u);
      t3q = cvt2_fp8<true>(mo2 * mo2, mo3 * mo3, t3q);
      *(unsigned*)(T38 + ptA * TVLD + rfb + 8 * qi) = t3q;
    }
    // Barrier B: T writes visible.
    __syncthreads();

    // ---- GEMM2: A = T (pt rows), B = W2 (dout cols), 4 K-steps of 16 ----
#pragma unroll
    for (int ks = 0; ks < 4; ++ks) {
      bf16x8 fam = *(const bf16x8*)(Tm + ptA * TMLD + ks * 16 + khalf * 8);
      long long fav = *(const long long*)(Tv8 + ptA * TVLD + ks * 16 + khalf * 8);
      long long f3  = *(const long long*)(T38 + ptA * TVLD + ks * 16 + khalf * 8);
#pragma unroll
      for (int d = 0; d < 2; ++d) {
        acc_mo[d] = __builtin_amdgcn_mfma_f32_32x32x16_bf16(fam, b2m[ks][d], acc_mo[d], 0, 0, 0);
        acc_vo[d] = __builtin_amdgcn_mfma_f32_32x32x16_fp8_fp8(fav, b2b[ks][d], acc_vo[d], 0, 0, 0);
        acc_vo[d] = __builtin_amdgcn_mfma_f32_32x32x16_fp8_fp8(f3, b2v[ks][d], acc_vo[d], 0, 0, 0);
      }
    }
  }

  // ---- epilogue: precision-weighted scatter (acc_vo carries x256 scale) ----
#pragma unroll
  for (int d = 0; d < 2; ++d) {
    int dout = (d0 + d) * 32 + col32;
#pragma unroll
    for (int rg = 0; rg < 16; ++rg) {
      int pt = ptblk * 32 + (rg & 3) + 8 * (rg >> 2) + 4 * khalf;
      float mo = acc_mo[d][rg];
      float vo = fmaf(acc_vo[d][rg], 0.00390625f, 1e-6f);
      float prec = fast_rcp(vo);
      size_t o = (size_t)sidx[pt] * DOUT + dout;
      unsafeAtomicAdd(acc_means + o, prec * mo);
      unsafeAtomicAdd(acc_vars + o, prec);
    }
  }
}

// ---------------- kernel 3: finalize ------------------------------------------
__global__ __launch_bounds__(256) void finalize_kernel(float* __restrict__ means,
                                                       float* __restrict__ vars) {
  int i = blockIdx.x * 256 + threadIdx.x;   // covers S*DOUT exactly
  float p  = vars[i];
  float pm = means[i];
  float var = 1.0f / p;
  means[i] = pm * var;
  vars[i]  = var;
}

extern "C" void kernel_launch(void* const* d_in, const int* in_sizes, int n_in,
                              void* d_out, int out_size, void* d_ws, size_t ws_size,
                              hipStream_t stream) {
  const float*    X     = (const float*)d_in[0];
  const unsigned* Xidx  = (const unsigned*)d_in[1];
  const float*    W1mu  = (const float*)d_in[2];
  const float*    W1var = (const float*)d_in[3];
  const float*    W2mu  = (const float*)d_in[4];
  const float*    W2var = (const float*)d_in[5];
  float* out = (float*)d_out;

  ushort_t* w1mu_bf = (ushort_t*)d_ws;                    // 262144 u16
  uchar_t*  w1var8  = (uchar_t*)(w1mu_bf + NRF * DIN);    // 262144 u8
  ushort_t* w2mu_bf = (ushort_t*)(w1var8 + NRF * DIN);    // 131072 u16
  uchar_t*  w2b8    = (uchar_t*)(w2mu_bf + NRF * DOUT);   // 131072 u8
  uchar_t*  w2var8  = w2b8 + NRF * DOUT;                  // 131072 u8
  int* flag = (int*)(w2var8 + NRF * DOUT);

  (void)hipMemsetAsync(d_out, 0, (size_t)out_size * sizeof(float), stream);
  detect_idx_kernel<<<1, 256, 0, stream>>>(Xidx, flag);
  convert_kernel<<<(NRF * DIN) / 4 / 256, 256, 0, stream>>>(
      W1mu, W1var, W2mu, W2var, w1mu_bf, w1var8, w2mu_bf, w2b8, w2var8);
  fused_kernel<<<NWG, 256, 0, stream>>>(
      X, Xidx, w1mu_bf, w1var8, w2mu_bf, w2b8, w2var8, flag,
      out, out + (size_t)SGRP * DOUT);
  finalize_kernel<<<(SGRP * DOUT) / 256, 256, 0, stream>>>(
      out, out + (size_t)SGRP * DOUT);
}

// Round 5
// 959.920 us; speedup vs baseline: 1.0663x; 1.0663x over previous
//
#include <hip/hip_runtime.h>

// DGP-RF embeddings, fused MFMA. Round 13: producer/consumer wave split.
// Ledger: R8=529us best. R9/R10 (occupancy) regressed: reg caps broke ILP.
// R11 (single-stream pipelining) regressed: compiler emits program order.
// R12 (32x32 shapes) regressed: 2 dependent MFMA chains + load sinking.
// R8 counters: Mfma 19.5 + VALU 36 + LDS ~25 -- nothing saturated, phases
// serialized with latency gaps. R13 forces overlap in HARDWARE: even waves
// run GEMM1+moments (producer), odd waves run GEMM2+atomics (consumer),
// 1 P + 1 C per SIMD. Per-wave code/ILP identical to R8; T double-buffered;
// ONE barrier per chunk (was two). Region(r) = P:chunk(r+1) || C:chunk(r).
// LDS 85.8KB -> 1 block/CU (512 thr, 8 waves, same 25% occ as R8).
// Predicted: Mfma ~27, VALU ~48, conflicts ~2.1e7, fused ~360-400us.

#define NPTS   131072
#define SGRP   16384
#define DIN    256
#define NRF    1024
#define DOUT   128
#define MT     64            // points per WG
#define NWG    (NPTS / MT)   // 2048

#define XLD    264   // bf16 X row stride
#define XQLD   264   // fp8 x^2 row stride
#define TMLD   72    // bf16 m' row stride
#define TVLD   72    // fp8 v'/m'^2 row stride

typedef unsigned short ushort_t;
typedef unsigned char  uchar_t;
typedef __attribute__((ext_vector_type(8))) short bf16x8;
typedef __attribute__((ext_vector_type(4))) float f32x4;
typedef __attribute__((ext_vector_type(4))) float f32x4v;

__device__ __forceinline__ unsigned short f2bf(float f) {
  unsigned u = __float_as_uint(f);
  u += 0x7fffu + ((u >> 16) & 1u);   // round-to-nearest-even
  return (unsigned short)(u >> 16);
}

// pack 2 floats -> 2 fp8 e4m3 bytes into (HI? bytes 2,3 : bytes 0,1) of old
template <bool HI>
__device__ __forceinline__ unsigned cvt2_fp8(float a, float b, unsigned old) {
#if __has_builtin(__builtin_amdgcn_cvt_pk_fp8_f32)
  return __builtin_amdgcn_cvt_pk_fp8_f32(a, b, old, HI);
#else
  auto enc = [](float x) -> unsigned {
    if (!(x > 0.00097656f)) return 0u;
    if (x >= 448.f) return 0x7Eu;
    union { float f; unsigned u; } v; v.f = x;
    int e = (int)(v.u >> 23) - 127;
    if (e < -6) { int n = (int)(x * 512.f + 0.5f); return (unsigned)n; }
    v.u += 0x0007FFFFu + ((v.u >> 20) & 1u);
    e = (int)(v.u >> 23) - 127;
    if (e > 8) return 0x7Eu;
    return (unsigned)(((e + 7) << 3) | ((v.u >> 20) & 7u));
  };
  unsigned p = (enc(a) | (enc(b) << 8));
  return HI ? ((old & 0x0000ffffu) | (p << 16)) : ((old & 0xffff0000u) | p);
#endif
}

__device__ __forceinline__ float fast_rcp(float x) {
#if __has_builtin(__builtin_amdgcn_rcpf)
  return __builtin_amdgcn_rcpf(x);
#else
  return 1.0f / x;
#endif
}
__device__ __forceinline__ float fast_rsq(float x) {
#if __has_builtin(__builtin_amdgcn_rsqf)
  return __builtin_amdgcn_rsqf(x);
#else
  return rsqrtf(x);
#endif
}
__device__ __forceinline__ float fast_exp2(float x) {
#if __has_builtin(__builtin_amdgcn_exp2f)
  return __builtin_amdgcn_exp2f(x);
#else
  return exp2f(x);
#endif
}

// Exact Gaussian-ReLU moments (A&S 7.1.26 erf, one shared exp2).
__device__ __forceinline__ void relu_moments(float mu, float v,
                                             float& mo, float& vo) {
  float vpe = v + 1e-8f;
  float rsq = fast_rsq(vpe);
  float s   = vpe * rsq;
  float z   = mu * rsq;
  float E   = fast_exp2(-0.7213475204444817f * z * z);  // exp(-z^2/2)
  float x   = 0.70710678118654752f * fabsf(z);
  float t   = fast_rcp(fmaf(0.3275911f, x, 1.0f));
  float poly = t * fmaf(t, fmaf(t, fmaf(t, fmaf(t, 1.061405429f, -1.453152027f),
                                        1.421413741f), -0.284496736f), 0.254829592f);
  float q   = 0.5f * poly * E;
  float Phi = (z >= 0.0f) ? (1.0f - q) : q;
  float phi = 0.3989422804014327f * E;
  float sphi = s * phi;
  mo = fmaf(mu, Phi, sphi);
  float ey2 = fmaf(fmaf(mu, mu, v), Phi, mu * sphi);
  vo = fmaxf(fmaf(-mo, mo, ey2), 1e-6f);
}

// ---------------- kernel 0: detect whether X_idx is int32 or int64 -------------
__global__ void detect_idx_kernel(const unsigned* __restrict__ raw,
                                  int* __restrict__ flag) {
  __shared__ int any_nz;
  if (threadIdx.x == 0) any_nz = 0;
  __syncthreads();
  if (raw[2 * threadIdx.x + 1] != 0u) atomicOr(&any_nz, 1);
  __syncthreads();
  if (threadIdx.x == 0) *flag = (any_nz == 0) ? 1 : 0;   // 1 => int64
}

// ---------------- kernel 1: convert weights (bf16 mean path, fp8 var path) ----
__global__ __launch_bounds__(256) void convert_kernel(
    const float* __restrict__ W1mu, const float* __restrict__ W1var,
    const float* __restrict__ W2mu, const float* __restrict__ W2var,
    ushort_t* __restrict__ w1mu_bf, uchar_t* __restrict__ w1var8,
    ushort_t* __restrict__ w2mu_bf, uchar_t* __restrict__ w2b8,
    uchar_t* __restrict__ w2var8) {
  int i4 = (blockIdx.x * 256 + threadIdx.x) * 4;   // grid covers 262144
  {
    f32x4v m = *(const f32x4v*)(W1mu + i4);
    ushort4 b; b.x = f2bf(m[0]); b.y = f2bf(m[1]); b.z = f2bf(m[2]); b.w = f2bf(m[3]);
    *(ushort4*)(w1mu_bf + i4) = b;
    f32x4v v = *(const f32x4v*)(W1var + i4);
    unsigned p = cvt2_fp8<false>(v[0] * 256.f, v[1] * 256.f, 0u);
    p = cvt2_fp8<true>(v[2] * 256.f, v[3] * 256.f, p);
    *(unsigned*)(w1var8 + i4) = p;
  }
  if (i4 < NRF * DOUT) {
    f32x4v m = *(const f32x4v*)(W2mu + i4);
    f32x4v v = *(const f32x4v*)(W2var + i4);
    ushort4 b; b.x = f2bf(m[0]); b.y = f2bf(m[1]); b.z = f2bf(m[2]); b.w = f2bf(m[3]);
    *(ushort4*)(w2mu_bf + i4) = b;
    unsigned pb = cvt2_fp8<false>(fmaf(m[0], m[0], v[0]) * 256.f,
                                  fmaf(m[1], m[1], v[1]) * 256.f, 0u);
    pb = cvt2_fp8<true>(fmaf(m[2], m[2], v[2]) * 256.f,
                        fmaf(m[3], m[3], v[3]) * 256.f, pb);
    *(unsigned*)(w2b8 + i4) = pb;
    unsigned pv = cvt2_fp8<false>(v[0] * 256.f, v[1] * 256.f, 0u);
    pv = cvt2_fp8<true>(v[2] * 256.f, v[3] * 256.f, pv);
    *(unsigned*)(w2var8 + i4) = pv;
  }
}

// ---------------- kernel 2: fused DGP-RF block --------------------------------
__global__ __launch_bounds__(512, 1) void fused_kernel(
    const float* __restrict__ X,
    const unsigned* __restrict__ Xidx_raw,
    const ushort_t* __restrict__ W1mu, const uchar_t* __restrict__ W1var8,
    const ushort_t* __restrict__ W2mu, const uchar_t* __restrict__ W2b8,
    const uchar_t* __restrict__ W2var8,
    const int* __restrict__ flag64,
    float* __restrict__ acc_means, float* __restrict__ acc_vars) {
  __shared__ ushort_t Xb[MT * XLD];        // 33.8 KB bf16 x
  __shared__ uchar_t  Xq8[MT * XQLD];      // 16.9 KB fp8 x^2
  __shared__ ushort_t Tm[2][MT * TMLD];    // 18.4 KB bf16 m'   (double buffer)
  __shared__ uchar_t  Tv8[2][MT * TVLD];   //  9.2 KB fp8 v'
  __shared__ uchar_t  T38[2][MT * TVLD];   //  9.2 KB fp8 m'^2
  __shared__ int sidx[MT];                 // total ~85.8 KB -> 1 block/CU

  const int tid = threadIdx.x;
  const int p0  = blockIdx.x * MT;
  const int is64 = *flag64;

  if (tid < MT) {
    int p = p0 + tid;
    sidx[tid] = (int)(is64 ? Xidx_raw[2 * (size_t)p] : Xidx_raw[p]);
  }
  // stage X tile: bf16 x and fp8 x^2, converted once here (512 threads)
#pragma unroll
  for (int i = 0; i < 8; ++i) {
    int idx4 = i * 512 + tid;       // 0..4095 (64 rows x 64 float4)
    int row  = idx4 >> 6;
    int c4   = idx4 & 63;
    f32x4v xv = *(const f32x4v*)(X + (size_t)(p0 + row) * DIN + c4 * 4);
    ushort4 b;
    b.x = f2bf(xv[0]); b.y = f2bf(xv[1]); b.z = f2bf(xv[2]); b.w = f2bf(xv[3]);
    *(ushort4*)(Xb + row * XLD + c4 * 4) = b;
    unsigned q = cvt2_fp8<false>(xv[0] * xv[0], xv[1] * xv[1], 0u);
    q = cvt2_fp8<true>(xv[2] * xv[2], xv[3] * xv[3], q);
    *(unsigned*)(Xq8 + row * XQLD + c4 * 4) = q;
  }
  __syncthreads();

  const int lane = tid & 63;
  const int wave = tid >> 6;      // 0..7
  const int role = wave & 1;      // 0 = producer, 1 = consumer (mixed per SIMD)
  const int wid  = wave >> 1;     // role-local index 0..3
  const int l16  = lane & 15;
  const int quad = lane >> 4;
  const int qoff = quad * 8;

  if (role == 0) {
    // ================= PRODUCER: GEMM1 + moments -> T[c&1] =================
    const int col = wid * 16 + l16;   // chunk-local RF column
#pragma unroll 1
    for (int c = 0; c < 16; ++c) {
      const ushort_t* w1m = W1mu  + (size_t)(c * 64 + wid * 16 + l16) * DIN + qoff;
      const uchar_t*  w1v = W1var8 + (size_t)(c * 64 + wid * 16 + l16) * DIN + qoff;
      bf16x8 bmu[8]; long long bvr[8];
#pragma unroll
      for (int k = 0; k < 8; ++k) {
        bmu[k] = *(const bf16x8*)(w1m + k * 32);
        bvr[k] = *(const long long*)(w1v + k * 32);
      }
      f32x4 am[4], av[4];
#pragma unroll
      for (int mt = 0; mt < 4; ++mt) {
        am[mt] = (f32x4){0.f, 0.f, 0.f, 0.f};
        av[mt] = (f32x4){0.f, 0.f, 0.f, 0.f};
      }
#pragma unroll
      for (int k = 0; k < 8; ++k) {
#pragma unroll
        for (int mt = 0; mt < 4; ++mt) {
          bf16x8 ax = *(const bf16x8*)(Xb + (mt * 16 + l16) * XLD + k * 32 + qoff);
          long long aq = *(const long long*)(Xq8 + (mt * 16 + l16) * XQLD + k * 32 + qoff);
          am[mt] = __builtin_amdgcn_mfma_f32_16x16x32_bf16(ax, bmu[k], am[mt], 0, 0, 0);
          av[mt] = __builtin_amdgcn_mfma_f32_16x16x32_fp8_fp8(aq, bvr[k], av[mt], 0, 0, 0);
        }
      }
      // moments -> T[buf]
      const int buf = c & 1;
#pragma unroll
      for (int mt = 0; mt < 4; ++mt) {
#pragma unroll
        for (int r = 0; r < 4; ++r) {
          float mo, vo;
          relu_moments(am[mt][r], av[mt][r] * 0.00390625f, mo, vo);
          int row = mt * 16 + quad * 4 + r;
          Tm[buf][row * TMLD + col] = f2bf(mo);
          Tv8[buf][row * TVLD + col] = (uchar_t)(cvt2_fp8<false>(vo, vo, 0u) & 0xffu);
          T38[buf][row * TVLD + col] = (uchar_t)(cvt2_fp8<false>(mo * mo, mo * mo, 0u) & 0xffu);
        }
      }
      __syncthreads();   // barrier(c): T[c&1] published; consumers done w/ T[c&1] reads (iter c-2)
    }
  } else {
    // ================= CONSUMER: GEMM2 from T[c&1] + epilogue ===============
    const int nrow0 = (wid * 2 + 0) * 16 + l16;   // GEMM2 B rows (dout)
    const int nrow1 = (wid * 2 + 1) * 16 + l16;

    f32x4 acc_mo[4][2], acc_vo[4][2];
#pragma unroll
    for (int mt = 0; mt < 4; ++mt)
#pragma unroll
      for (int j = 0; j < 2; ++j) {
        acc_mo[mt][j] = (f32x4){0.f, 0.f, 0.f, 0.f};
        acc_vo[mt][j] = (f32x4){0.f, 0.f, 0.f, 0.f};
      }

#pragma unroll 1
    for (int c = 0; c < 16; ++c) {
      // preload W2 frags for chunk c (global; latency hides across barrier)
      const ushort_t* w2m0 = W2mu + (size_t)nrow0 * NRF + c * 64 + qoff;
      const ushort_t* w2m1 = W2mu + (size_t)nrow1 * NRF + c * 64 + qoff;
      const uchar_t* w2b0 = W2b8 + (size_t)nrow0 * NRF + c * 64 + qoff;
      const uchar_t* w2b1 = W2b8 + (size_t)nrow1 * NRF + c * 64 + qoff;
      const uchar_t* w2v0 = W2var8 + (size_t)nrow0 * NRF + c * 64 + qoff;
      const uchar_t* w2v1 = W2var8 + (size_t)nrow1 * NRF + c * 64 + qoff;
      bf16x8 b2m[2][2]; long long b2b[2][2], b2v[2][2];
#pragma unroll
      for (int k2 = 0; k2 < 2; ++k2) {
        b2m[0][k2] = *(const bf16x8*)(w2m0 + k2 * 32);
        b2m[1][k2] = *(const bf16x8*)(w2m1 + k2 * 32);
        b2b[0][k2] = *(const long long*)(w2b0 + k2 * 32);
        b2b[1][k2] = *(const long long*)(w2b1 + k2 * 32);
        b2v[0][k2] = *(const long long*)(w2v0 + k2 * 32);
        b2v[1][k2] = *(const long long*)(w2v1 + k2 * 32);
      }

      __syncthreads();   // barrier(c): wait for producers to publish T[c&1]

      const int buf = c & 1;
#pragma unroll
      for (int k2 = 0; k2 < 2; ++k2) {
#pragma unroll
        for (int mt = 0; mt < 4; ++mt) {
          int ar = mt * 16 + l16;
          bf16x8 fam = *(const bf16x8*)(Tm[buf] + ar * TMLD + k2 * 32 + qoff);
          long long fav = *(const long long*)(Tv8[buf] + ar * TVLD + k2 * 32 + qoff);
          long long f3  = *(const long long*)(T38[buf] + ar * TVLD + k2 * 32 + qoff);
          acc_mo[mt][0] = __builtin_amdgcn_mfma_f32_16x16x32_bf16(fam, b2m[0][k2], acc_mo[mt][0], 0, 0, 0);
          acc_mo[mt][1] = __builtin_amdgcn_mfma_f32_16x16x32_bf16(fam, b2m[1][k2], acc_mo[mt][1], 0, 0, 0);
          acc_vo[mt][0] = __builtin_amdgcn_mfma_f32_16x16x32_fp8_fp8(fav, b2b[0][k2], acc_vo[mt][0], 0, 0, 0);
          acc_vo[mt][1] = __builtin_amdgcn_mfma_f32_16x16x32_fp8_fp8(fav, b2b[1][k2], acc_vo[mt][1], 0, 0, 0);
          acc_vo[mt][0] = __builtin_amdgcn_mfma_f32_16x16x32_fp8_fp8(f3, b2v[0][k2], acc_vo[mt][0], 0, 0, 0);
          acc_vo[mt][1] = __builtin_amdgcn_mfma_f32_16x16x32_fp8_fp8(f3, b2v[1][k2], acc_vo[mt][1], 0, 0, 0);
        }
      }
    }

    // ---- epilogue: precision-weighted scatter (acc_vo carries x256 scale) ----
#pragma unroll
    for (int mt = 0; mt < 4; ++mt)
#pragma unroll
      for (int j = 0; j < 2; ++j) {
        int dim = (wid * 2 + j) * 16 + l16;
#pragma unroll
        for (int r = 0; r < 4; ++r) {
          int prow = mt * 16 + quad * 4 + r;
          float mo = acc_mo[mt][j][r];
          float vo = fmaf(acc_vo[mt][j][r], 0.00390625f, 1e-6f);
          float prec = fast_rcp(vo);
          size_t o = (size_t)sidx[prow] * DOUT + dim;
          unsafeAtomicAdd(acc_means + o, prec * mo);
          unsafeAtomicAdd(acc_vars + o, prec);
        }
      }
  }
}

// ---------------- kernel 3: finalize ------------------------------------------
__global__ __launch_bounds__(256) void finalize_kernel(float* __restrict__ means,
                                                       float* __restrict__ vars) {
  int i = blockIdx.x * 256 + threadIdx.x;   // covers S*DOUT exactly
  float p  = vars[i];
  float pm = means[i];
  float var = 1.0f / p;
  means[i] = pm * var;
  vars[i]  = var;
}

extern "C" void kernel_launch(void* const* d_in, const int* in_sizes, int n_in,
                              void* d_out, int out_size, void* d_ws, size_t ws_size,
                              hipStream_t stream) {
  const float*    X     = (const float*)d_in[0];
  const unsigned* Xidx  = (const unsigned*)d_in[1];
  const float*    W1mu  = (const float*)d_in[2];
  const float*    W1var = (const float*)d_in[3];
  const float*    W2mu  = (const float*)d_in[4];
  const float*    W2var = (const float*)d_in[5];
  float* out = (float*)d_out;

  ushort_t* w1mu_bf = (ushort_t*)d_ws;                    // 262144 u16
  uchar_t*  w1var8  = (uchar_t*)(w1mu_bf + NRF * DIN);    // 262144 u8
  ushort_t* w2mu_bf = (ushort_t*)(w1var8 + NRF * DIN);    // 131072 u16
  uchar_t*  w2b8    = (uchar_t*)(w2mu_bf + NRF * DOUT);   // 131072 u8
  uchar_t*  w2var8  = w2b8 + NRF * DOUT;                  // 131072 u8
  int* flag = (int*)(w2var8 + NRF * DOUT);

  (void)hipMemsetAsync(d_out, 0, (size_t)out_size * sizeof(float), stream);
  detect_idx_kernel<<<1, 256, 0, stream>>>(Xidx, flag);
  convert_kernel<<<(NRF * DIN) / 4 / 256, 256, 0, stream>>>(
      W1mu, W1var, W2mu, W2var, w1mu_bf, w1var8, w2mu_bf, w2b8, w2var8);
  fused_kernel<<<NWG, 512, 0, stream>>>(
      X, Xidx, w1mu_bf, w1var8, w2mu_bf, w2b8, w2var8, flag,
      out, out + (size_t)SGRP * DOUT);
  finalize_kernel<<<(SGRP * DOUT) / 256, 256, 0, stream>>>(
      out, out + (size_t)SGRP * DOUT);
}

// Round 6
// 668.619 us; speedup vs baseline: 1.5308x; 1.4357x over previous
//
#include <hip/hip_runtime.h>

// DGP-RF embeddings, fused MFMA. Round 14: R8 structure + moments LUT.
// Ledger: R8=529us best. R9/R10 (occupancy), R11 (sw pipelining), R12 (32x32),
// R13 (wave specialization) ALL regressed -- R8's balanced 2-blk/CU structure
// is a structural local optimum; stop touching it.
// R14 attacks the biggest pipe (VALU 36%): moments math is 27 VALU (3 trans)
// per value but outputs only need bf16/fp8 precision. Exact identity:
//   m' = s*h(z), v' = vpe*w(z),  z = mu/s, s^2 = vpe = v+1e-8
//   h(z) = z*Phi+phi, w(z) = (z^2+1)Phi + z*phi - h^2   (z-only functions)
// -> 256-entry lerp table {h,dh,w,dw} in LDS (4KB), one ds_read_b128 + 2 fma.
// Lerp err ~2e-4 << bf16 rounding. Table built once by init kernel w/ erff.
// Per value: ~16 VALU (1 trans) + 1 LDS gather. Everything else == R8.
// Predicted: VALU ~27, Mfma ~23, conflicts 2.5-3.5e7, LDS 73728,
// fused ~450-490us. Falsifier: no speedup => VALU wasn't critical path.

#define NPTS   131072
#define SGRP   16384
#define DIN    256
#define NRF    1024
#define DOUT   128
#define MT     64            // points per WG
#define NWG    (NPTS / MT)   // 2048

#define XLD    264   // bf16 X row stride
#define XQLD   264   // fp8 x^2 row stride
#define TMLD   72    // bf16 m' row stride
#define TVLD   72    // fp8 v'/m'^2 row stride

typedef unsigned short ushort_t;
typedef unsigned char  uchar_t;
typedef __attribute__((ext_vector_type(8))) short bf16x8;
typedef __attribute__((ext_vector_type(4))) float f32x4;
typedef __attribute__((ext_vector_type(4))) float f32x4v;

__device__ __forceinline__ unsigned short f2bf(float f) {
  unsigned u = __float_as_uint(f);
  u += 0x7fffu + ((u >> 16) & 1u);   // round-to-nearest-even
  return (unsigned short)(u >> 16);
}

// pack 2 floats -> 2 fp8 e4m3 bytes into (HI? bytes 2,3 : bytes 0,1) of old
template <bool HI>
__device__ __forceinline__ unsigned cvt2_fp8(float a, float b, unsigned old) {
#if __has_builtin(__builtin_amdgcn_cvt_pk_fp8_f32)
  return __builtin_amdgcn_cvt_pk_fp8_f32(a, b, old, HI);
#else
  auto enc = [](float x) -> unsigned {
    if (!(x > 0.00097656f)) return 0u;
    if (x >= 448.f) return 0x7Eu;
    union { float f; unsigned u; } v; v.f = x;
    int e = (int)(v.u >> 23) - 127;
    if (e < -6) { int n = (int)(x * 512.f + 0.5f); return (unsigned)n; }
    v.u += 0x0007FFFFu + ((v.u >> 20) & 1u);
    e = (int)(v.u >> 23) - 127;
    if (e > 8) return 0x7Eu;
    return (unsigned)(((e + 7) << 3) | ((v.u >> 20) & 7u));
  };
  unsigned p = (enc(a) | (enc(b) << 8));
  return HI ? ((old & 0x0000ffffu) | (p << 16)) : ((old & 0xffff0000u) | p);
#endif
}

__device__ __forceinline__ float fast_rcp(float x) {
#if __has_builtin(__builtin_amdgcn_rcpf)
  return __builtin_amdgcn_rcpf(x);
#else
  return 1.0f / x;
#endif
}
__device__ __forceinline__ float fast_rsq(float x) {
#if __has_builtin(__builtin_amdgcn_rsqf)
  return __builtin_amdgcn_rsqf(x);
#else
  return rsqrtf(x);
#endif
}

// ---------------- kernel 0: detect whether X_idx is int32 or int64 -------------
__global__ void detect_idx_kernel(const unsigned* __restrict__ raw,
                                  int* __restrict__ flag) {
  __shared__ int any_nz;
  if (threadIdx.x == 0) any_nz = 0;
  __syncthreads();
  if (raw[2 * threadIdx.x + 1] != 0u) atomicOr(&any_nz, 1);
  __syncthreads();
  if (threadIdx.x == 0) *flag = (any_nz == 0) ? 1 : 0;   // 1 => int64
}

// ---------------- kernel 0b: build 256-entry lerp table for h(z), w(z) --------
// entry i covers z in [i/16-8, i/16-8+1/16); stores {h0, h1-h0, w0, w1-w0}.
__global__ void moments_table_kernel(float4* __restrict__ tab) {
  int i = threadIdx.x;   // 0..255
  float z0 = (float)i * 0.0625f - 8.0f;
  float h[2], w[2];
#pragma unroll
  for (int j = 0; j < 2; ++j) {
    float z = z0 + 0.0625f * j;
    float Phi = 0.5f * (1.0f + erff(z * 0.70710678118654752f));
    float phi = 0.3989422804014327f * expf(-0.5f * z * z);
    float hh = z * Phi + phi;
    float gg = (z * z + 1.0f) * Phi + z * phi;
    h[j] = hh;
    w[j] = gg - hh * hh;
  }
  tab[i] = make_float4(h[0], h[1] - h[0], w[0], w[1] - w[0]);
}

// ---------------- kernel 1: convert weights (bf16 mean path, fp8 var path) ----
__global__ __launch_bounds__(256) void convert_kernel(
    const float* __restrict__ W1mu, const float* __restrict__ W1var,
    const float* __restrict__ W2mu, const float* __restrict__ W2var,
    ushort_t* __restrict__ w1mu_bf, uchar_t* __restrict__ w1var8,
    ushort_t* __restrict__ w2mu_bf, uchar_t* __restrict__ w2b8,
    uchar_t* __restrict__ w2var8) {
  int i4 = (blockIdx.x * 256 + threadIdx.x) * 4;   // grid covers 262144
  {
    f32x4v m = *(const f32x4v*)(W1mu + i4);
    ushort4 b; b.x = f2bf(m[0]); b.y = f2bf(m[1]); b.z = f2bf(m[2]); b.w = f2bf(m[3]);
    *(ushort4*)(w1mu_bf + i4) = b;
    f32x4v v = *(const f32x4v*)(W1var + i4);
    unsigned p = cvt2_fp8<false>(v[0] * 256.f, v[1] * 256.f, 0u);
    p = cvt2_fp8<true>(v[2] * 256.f, v[3] * 256.f, p);
    *(unsigned*)(w1var8 + i4) = p;
  }
  if (i4 < NRF * DOUT) {
    f32x4v m = *(const f32x4v*)(W2mu + i4);
    f32x4v v = *(const f32x4v*)(W2var + i4);
    ushort4 b; b.x = f2bf(m[0]); b.y = f2bf(m[1]); b.z = f2bf(m[2]); b.w = f2bf(m[3]);
    *(ushort4*)(w2mu_bf + i4) = b;
    unsigned pb = cvt2_fp8<false>(fmaf(m[0], m[0], v[0]) * 256.f,
                                  fmaf(m[1], m[1], v[1]) * 256.f, 0u);
    pb = cvt2_fp8<true>(fmaf(m[2], m[2], v[2]) * 256.f,
                        fmaf(m[3], m[3], v[3]) * 256.f, pb);
    *(unsigned*)(w2b8 + i4) = pb;
    unsigned pv = cvt2_fp8<false>(v[0] * 256.f, v[1] * 256.f, 0u);
    pv = cvt2_fp8<true>(v[2] * 256.f, v[3] * 256.f, pv);
    *(unsigned*)(w2var8 + i4) = pv;
  }
}

// ---------------- kernel 2: fused DGP-RF block --------------------------------
__global__ __launch_bounds__(256, 2) void fused_kernel(
    const float* __restrict__ X,
    const unsigned* __restrict__ Xidx_raw,
    const ushort_t* __restrict__ W1mu, const uchar_t* __restrict__ W1var8,
    const ushort_t* __restrict__ W2mu, const uchar_t* __restrict__ W2b8,
    const uchar_t* __restrict__ W2var8,
    const float4* __restrict__ htab_g,
    const int* __restrict__ flag64,
    float* __restrict__ acc_means, float* __restrict__ acc_vars) {
  __shared__ ushort_t Xb[MT * XLD];    // 33.8 KB bf16 x
  __shared__ uchar_t  Xq8[MT * XQLD];  // 16.9 KB fp8 x^2
  __shared__ ushort_t Tm[MT * TMLD];   //  9.2 KB bf16 m'
  __shared__ uchar_t  Tv8[MT * TVLD];  //  4.6 KB fp8 v'
  __shared__ uchar_t  T38[MT * TVLD];  //  4.6 KB fp8 m'^2
  __shared__ float4   htab[256];       //  4.0 KB moments lerp table
  __shared__ int sidx[MT];

  const int tid = threadIdx.x;
  const int p0  = blockIdx.x * MT;
  const int is64 = *flag64;

  if (tid < MT) {
    int p = p0 + tid;
    sidx[tid] = (int)(is64 ? Xidx_raw[2 * (size_t)p] : Xidx_raw[p]);
  }
  htab[tid] = htab_g[tid];   // 256 threads, 256 entries
  // stage X tile: bf16 x and fp8 x^2, converted once here
#pragma unroll
  for (int i = 0; i < 16; ++i) {
    int idx4 = i * 256 + tid;       // 0..4095 (64 rows x 64 float4)
    int row  = idx4 >> 6;
    int c4   = idx4 & 63;
    f32x4v xv = *(const f32x4v*)(X + (size_t)(p0 + row) * DIN + c4 * 4);
    ushort4 b;
    b.x = f2bf(xv[0]); b.y = f2bf(xv[1]); b.z = f2bf(xv[2]); b.w = f2bf(xv[3]);
    *(ushort4*)(Xb + row * XLD + c4 * 4) = b;
    unsigned q = cvt2_fp8<false>(xv[0] * xv[0], xv[1] * xv[1], 0u);
    q = cvt2_fp8<true>(xv[2] * xv[2], xv[3] * xv[3], q);
    *(unsigned*)(Xq8 + row * XQLD + c4 * 4) = q;
  }
  __syncthreads();

  const int lane = tid & 63;
  const int wave = tid >> 6;
  const int l16  = lane & 15;
  const int quad = lane >> 4;
  const int qoff = quad * 8;

  const int nrow0 = (wave * 2 + 0) * 16 + l16;   // GEMM2 B rows (dout)
  const int nrow1 = (wave * 2 + 1) * 16 + l16;

  f32x4 acc_mo[4][2], acc_vo[4][2];
#pragma unroll
  for (int mt = 0; mt < 4; ++mt)
#pragma unroll
    for (int j = 0; j < 2; ++j) {
      acc_mo[mt][j] = (f32x4){0.f, 0.f, 0.f, 0.f};
      acc_vo[mt][j] = (f32x4){0.f, 0.f, 0.f, 0.f};
    }

#pragma unroll 1
  for (int c = 0; c < 16; ++c) {   // 16 chunks x 64 RFs
    // ---- GEMM1: this wave owns RF rows c*64 + wave*16 + l16 ----
    const ushort_t* w1m = W1mu  + (size_t)(c * 64 + wave * 16 + l16) * DIN + qoff;
    const uchar_t*  w1v = W1var8 + (size_t)(c * 64 + wave * 16 + l16) * DIN + qoff;
    bf16x8 bmu[8]; long long bvr[8];
#pragma unroll
    for (int k = 0; k < 8; ++k) {
      bmu[k] = *(const bf16x8*)(w1m + k * 32);
      bvr[k] = *(const long long*)(w1v + k * 32);
    }
    f32x4 am[4], av[4];
#pragma unroll
    for (int mt = 0; mt < 4; ++mt) {
      am[mt] = (f32x4){0.f, 0.f, 0.f, 0.f};
      av[mt] = (f32x4){0.f, 0.f, 0.f, 0.f};
    }
#pragma unroll
    for (int k = 0; k < 8; ++k) {
#pragma unroll
      for (int mt = 0; mt < 4; ++mt) {
        bf16x8 ax = *(const bf16x8*)(Xb + (mt * 16 + l16) * XLD + k * 32 + qoff);
        long long aq = *(const long long*)(Xq8 + (mt * 16 + l16) * XQLD + k * 32 + qoff);
        am[mt] = __builtin_amdgcn_mfma_f32_16x16x32_bf16(ax, bmu[k], am[mt], 0, 0, 0);
        av[mt] = __builtin_amdgcn_mfma_f32_16x16x32_fp8_fp8(aq, bvr[k], av[mt], 0, 0, 0);
      }
    }

    // ---- preload GEMM2 B (independent of LDS; overlaps moments) ----
    const ushort_t* w2m0 = W2mu + (size_t)nrow0 * NRF + c * 64 + qoff;
    const ushort_t* w2m1 = W2mu + (size_t)nrow1 * NRF + c * 64 + qoff;
    const uchar_t* w2b0 = W2b8 + (size_t)nrow0 * NRF + c * 64 + qoff;
    const uchar_t* w2b1 = W2b8 + (size_t)nrow1 * NRF + c * 64 + qoff;
    const uchar_t* w2v0 = W2var8 + (size_t)nrow0 * NRF + c * 64 + qoff;
    const uchar_t* w2v1 = W2var8 + (size_t)nrow1 * NRF + c * 64 + qoff;
    bf16x8 b2m[2][2]; long long b2b[2][2], b2v[2][2];
#pragma unroll
    for (int k2 = 0; k2 < 2; ++k2) {
      b2m[0][k2] = *(const bf16x8*)(w2m0 + k2 * 32);
      b2m[1][k2] = *(const bf16x8*)(w2m1 + k2 * 32);
      b2b[0][k2] = *(const long long*)(w2b0 + k2 * 32);
      b2b[1][k2] = *(const long long*)(w2b1 + k2 * 32);
      b2v[0][k2] = *(const long long*)(w2v0 + k2 * 32);
      b2v[1][k2] = *(const long long*)(w2v1 + k2 * 32);
    }

    // Barrier A: prior chunk's GEMM2 T-reads complete before overwrite.
    __syncthreads();

    // ---- ReLU moments via LUT -> Tm (bf16), Tv8 (fp8 v'), T38 (fp8 m'^2) ----
    const int col = wave * 16 + l16;   // chunk-local column
#pragma unroll
    for (int mt = 0; mt < 4; ++mt) {
#pragma unroll
      for (int r = 0; r < 4; ++r) {
        float mu  = am[mt][r];
        float vpe = fmaf(av[mt][r], 0.00390625f, 1e-8f);  // descale + eps
        float rsq = fast_rsq(vpe);
        float z   = mu * rsq;
        float s   = vpe * rsq;
        float zc  = fminf(fmaxf(z, -8.0f), 7.96875f);
        float u   = fmaf(zc, 16.0f, 128.0f);              // [0, 255.5]
        float fu  = floorf(u);
        float f   = u - fu;
        float4 hv = htab[(int)fu];
        float h   = fmaf(f, hv.y, hv.x);
        float w   = fmaf(f, hv.w, hv.z);
        float mo  = (z > 7.9f) ? mu : s * h;              // exact linear tail
        float vo  = fmaxf(vpe * w, 1e-6f);
        int row = mt * 16 + quad * 4 + r;
        Tm[row * TMLD + col] = f2bf(mo);
        Tv8[row * TVLD + col] = (uchar_t)(cvt2_fp8<false>(vo, vo, 0u) & 0xffu);
        T38[row * TVLD + col] = (uchar_t)(cvt2_fp8<false>(mo * mo, mo * mo, 0u) & 0xffu);
      }
    }
    // Barrier B: T writes visible.
    __syncthreads();

    // ---- GEMM2 over this 64-RF chunk (2 K-steps) ----
#pragma unroll
    for (int k2 = 0; k2 < 2; ++k2) {
#pragma unroll
      for (int mt = 0; mt < 4; ++mt) {
        int ar = mt * 16 + l16;
        bf16x8 fam = *(const bf16x8*)(Tm + ar * TMLD + k2 * 32 + qoff);
        long long fav = *(const long long*)(Tv8 + ar * TVLD + k2 * 32 + qoff);
        long long f3  = *(const long long*)(T38 + ar * TVLD + k2 * 32 + qoff);
        acc_mo[mt][0] = __builtin_amdgcn_mfma_f32_16x16x32_bf16(fam, b2m[0][k2], acc_mo[mt][0], 0, 0, 0);
        acc_mo[mt][1] = __builtin_amdgcn_mfma_f32_16x16x32_bf16(fam, b2m[1][k2], acc_mo[mt][1], 0, 0, 0);
        acc_vo[mt][0] = __builtin_amdgcn_mfma_f32_16x16x32_fp8_fp8(fav, b2b[0][k2], acc_vo[mt][0], 0, 0, 0);
        acc_vo[mt][1] = __builtin_amdgcn_mfma_f32_16x16x32_fp8_fp8(fav, b2b[1][k2], acc_vo[mt][1], 0, 0, 0);
        acc_vo[mt][0] = __builtin_amdgcn_mfma_f32_16x16x32_fp8_fp8(f3, b2v[0][k2], acc_vo[mt][0], 0, 0, 0);
        acc_vo[mt][1] = __builtin_amdgcn_mfma_f32_16x16x32_fp8_fp8(f3, b2v[1][k2], acc_vo[mt][1], 0, 0, 0);
      }
    }
  }

  // ---- epilogue: precision-weighted scatter (acc_vo carries x256 scale) ----
#pragma unroll
  for (int mt = 0; mt < 4; ++mt)
#pragma unroll
    for (int j = 0; j < 2; ++j) {
      int dim = (wave * 2 + j) * 16 + l16;
#pragma unroll
      for (int r = 0; r < 4; ++r) {
        int prow = mt * 16 + quad * 4 + r;
        float mo = acc_mo[mt][j][r];
        float vo = fmaf(acc_vo[mt][j][r], 0.00390625f, 1e-6f);
        float prec = fast_rcp(vo);
        size_t o = (size_t)sidx[prow] * DOUT + dim;
        unsafeAtomicAdd(acc_means + o, prec * mo);
        unsafeAtomicAdd(acc_vars + o, prec);
      }
    }
}

// ---------------- kernel 3: finalize ------------------------------------------
__global__ __launch_bounds__(256) void finalize_kernel(float* __restrict__ means,
                                                       float* __restrict__ vars) {
  int i = blockIdx.x * 256 + threadIdx.x;   // covers S*DOUT exactly
  float p  = vars[i];
  float pm = means[i];
  float var = 1.0f / p;
  means[i] = pm * var;
  vars[i]  = var;
}

extern "C" void kernel_launch(void* const* d_in, const int* in_sizes, int n_in,
                              void* d_out, int out_size, void* d_ws, size_t ws_size,
                              hipStream_t stream) {
  const float*    X     = (const float*)d_in[0];
  const unsigned* Xidx  = (const unsigned*)d_in[1];
  const float*    W1mu  = (const float*)d_in[2];
  const float*    W1var = (const float*)d_in[3];
  const float*    W2mu  = (const float*)d_in[4];
  const float*    W2var = (const float*)d_in[5];
  float* out = (float*)d_out;

  ushort_t* w1mu_bf = (ushort_t*)d_ws;                    // 524288 B
  uchar_t*  w1var8  = (uchar_t*)(w1mu_bf + NRF * DIN);    // 262144 B
  ushort_t* w2mu_bf = (ushort_t*)(w1var8 + NRF * DIN);    // 262144 B
  uchar_t*  w2b8    = (uchar_t*)(w2mu_bf + NRF * DOUT);   // 131072 B
  uchar_t*  w2var8  = w2b8 + NRF * DOUT;                  // 131072 B
  float4*   htab    = (float4*)(w2var8 + NRF * DOUT);     // 4096 B (16-aligned)
  int* flag = (int*)(htab + 256);

  (void)hipMemsetAsync(d_out, 0, (size_t)out_size * sizeof(float), stream);
  detect_idx_kernel<<<1, 256, 0, stream>>>(Xidx, flag);
  moments_table_kernel<<<1, 256, 0, stream>>>(htab);
  convert_kernel<<<(NRF * DIN) / 4 / 256, 256, 0, stream>>>(
      W1mu, W1var, W2mu, W2var, w1mu_bf, w1var8, w2mu_bf, w2b8, w2var8);
  fused_kernel<<<NWG, 256, 0, stream>>>(
      X, Xidx, w1mu_bf, w1var8, w2mu_bf, w2b8, w2var8, htab, flag,
      out, out + (size_t)SGRP * DOUT);
  finalize_kernel<<<(SGRP * DOUT) / 256, 256, 0, stream>>>(
      out, out + (size_t)SGRP * DOUT);
}